// Round 6
// baseline (632.244 us; speedup 1.0000x reference)
//
#include <hip/hip_runtime.h>
#include <math.h>

// ---------------------------------------------------------------------------
// Types / helpers
// ---------------------------------------------------------------------------
typedef __bf16 bf16x8 __attribute__((ext_vector_type(8)));
typedef float floatx4 __attribute__((ext_vector_type(4)));

__device__ __forceinline__ unsigned short f32_to_bf16(float f) {
  unsigned int u = __float_as_uint(f);
  u = u + 0x7FFFu + ((u >> 16) & 1u);   // RNE; inputs finite
  return (unsigned short)(u >> 16);
}

// async global->LDS, 16B/lane. GLOBAL ptr must include the per-lane offset
// (lane*8 shorts); LDS base is wave-uniform, HW scatters lane i to +i*16B.
// R4/R5 bug: fattn passed a wave-uniform global ptr -> 64x replicated bytes.
__device__ __forceinline__ void gld_lds16(const unsigned short* g,
                                          unsigned short* l) {
  __builtin_amdgcn_global_load_lds(
      (const __attribute__((address_space(1))) unsigned int*)g,
      (__attribute__((address_space(3))) unsigned int*)l, 16, 0, 0);
}

// ---------------------------------------------------------------------------
// fp32 -> bf16 cast (float4 -> ushort4)
// ---------------------------------------------------------------------------
__global__ void cast_kernel(const float* __restrict__ in,
                            unsigned short* __restrict__ out, int n4) {
  int i = blockIdx.x * blockDim.x + threadIdx.x;
  if (i >= n4) return;
  const float4 v = reinterpret_cast<const float4*>(in)[i];
  ushort4 o;
  o.x = f32_to_bf16(v.x); o.y = f32_to_bf16(v.y);
  o.z = f32_to_bf16(v.z); o.w = f32_to_bf16(v.w);
  reinterpret_cast<ushort4*>(out)[i] = o;
}

// three weights -> one concatenated bf16 buffer [Wq;Wk;Wv] (6144 x 2048)
__global__ void cast3_kernel(const float* __restrict__ w0,
                             const float* __restrict__ w1,
                             const float* __restrict__ w2,
                             unsigned short* __restrict__ out, int n4each) {
  int i = blockIdx.x * blockDim.x + threadIdx.x;
  if (i >= 3 * n4each) return;
  const int which = i / n4each;
  const int off = i - which * n4each;
  const float* src = (which == 0) ? w0 : (which == 1) ? w1 : w2;
  const float4 v = reinterpret_cast<const float4*>(src)[off];
  ushort4 o;
  o.x = f32_to_bf16(v.x); o.y = f32_to_bf16(v.y);
  o.z = f32_to_bf16(v.z); o.w = f32_to_bf16(v.w);
  reinterpret_cast<ushort4*>(out)[i] = o;
}

// bias concat: bqkv[0:2048)=bq, [2048:4096)=bk, [4096:6144)=bv
__global__ void bcat_kernel(const float* __restrict__ bq,
                            const float* __restrict__ bk,
                            const float* __restrict__ bv,
                            float* __restrict__ out) {
  int i = blockIdx.x * blockDim.x + threadIdx.x;  // 0..6143
  const int which = i >> 11, off = i & 2047;
  out[i] = (which == 0) ? bq[off] : (which == 1) ? bk[off] : bv[off];
}

// ---------------------------------------------------------------------------
// RoPE cos/sin table: tab[s*64+i] = (cos, sin) of s / 10000^(i/64).
// Built with libm cosf/sinf (full range reduction) — native v_sin/v_cos are
// only valid to ~±1608 rad and angles here reach 2047 rad.
// ---------------------------------------------------------------------------
__global__ void rope_table_kernel(float2* __restrict__ tab, int total) {
  int idx = blockIdx.x * blockDim.x + threadIdx.x;
  if (idx >= total) return;
  const int s = idx >> 6, i = idx & 63;
  const float inv = powf(10000.0f, -(float)i * (1.0f / 64.0f));
  const float ang = (float)s * inv;
  tab[idx] = make_float2(cosf(ang), sinf(ang));
}

// ---------------------------------------------------------------------------
// Fused GEMM: C[m][n] = sum_k A[m][k]*B[n][k] + bias[n]
// 128x128 tile, BK=64, 4 waves, 4x4 of 16x16x32 MFMA. global_load_lds
// staging into unpadded LDS with XOR chunk swizzle on the GLOBAL address.
// EPI=0: fp32 out + bias (N=2048).
// EPI=1: QKV mega-GEMM (N=6144). Per col>>11:
//   0 -> RoPE (table) * qscale -> Qbb row-major [m][2048]
//   1 -> RoPE (table) -> Kh [bh][kt][d'] with d-chunk swizzle (key kt&15)
//   2 -> Vt3 [bh][kb][d][ks'] with ks-chunk swizzle (key d&7)
// ---------------------------------------------------------------------------
template <int EPI>
__global__ __launch_bounds__(256) void gemm_fused(
    const unsigned short* __restrict__ A, const unsigned short* __restrict__ B,
    const float* __restrict__ bias, float* __restrict__ Cf,
    unsigned short* __restrict__ Qo, unsigned short* __restrict__ Ko,
    unsigned short* __restrict__ Vo, const float2* __restrict__ tab,
    float scl, int M, int N, int K) {
  __shared__ unsigned short As[128 * 64];
  __shared__ unsigned short Bs[128 * 64];
  const int t = threadIdx.x;
  const int lane = t & 63;
  const int w = t >> 6;
  const int bm = blockIdx.y * 128;
  const int bn = blockIdx.x * 128;
  const int wm = (w & 1) * 64;
  const int wn = (w >> 1) * 64;
  const int m16 = lane & 15;
  const int quad = lane >> 4;
  const int key = m16 & 7;

  const int lr = lane >> 3;
  const int lc = ((lane & 7) ^ lr) * 8;

  floatx4 acc[4][4];
#pragma unroll
  for (int i = 0; i < 4; ++i)
#pragma unroll
    for (int j = 0; j < 4; ++j) acc[i][j] = floatx4{0.f, 0.f, 0.f, 0.f};

  const unsigned short* Abase = A + (size_t)(bm + w * 32 + lr) * K + lc;
  const unsigned short* Bbase = B + (size_t)(bn + w * 32 + lr) * K + lc;

  for (int k0 = 0; k0 < K; k0 += 64) {
    __syncthreads();
#pragma unroll
    for (int it = 0; it < 4; ++it) {
      gld_lds16(Abase + (size_t)it * 8 * K + k0, &As[(w * 4 + it) * 512]);
      gld_lds16(Bbase + (size_t)it * 8 * K + k0, &Bs[(w * 4 + it) * 512]);
    }
    __syncthreads();
#pragma unroll
    for (int ks = 0; ks < 64; ks += 32) {
      const int ck = ks >> 3;  // 0 or 4
      bf16x8 af[4], bfr[4];
#pragma unroll
      for (int i = 0; i < 4; ++i)
        af[i] = *reinterpret_cast<const bf16x8*>(
            &As[(wm + i * 16 + m16) * 64 + ((ck | quad) ^ key) * 8]);
#pragma unroll
      for (int j = 0; j < 4; ++j)
        bfr[j] = *reinterpret_cast<const bf16x8*>(
            &Bs[(wn + j * 16 + m16) * 64 + ((ck | quad) ^ key) * 8]);
#pragma unroll
      for (int i = 0; i < 4; ++i)
#pragma unroll
        for (int j = 0; j < 4; ++j)
          acc[i][j] = __builtin_amdgcn_mfma_f32_16x16x32_bf16(
              af[i], bfr[j], acc[i][j], 0, 0, 0);
    }
  }

  // epilogue: C/D layout col=lane&15, row=quad*4+reg  [m89/m91 verified]
#pragma unroll
  for (int i = 0; i < 4; ++i) {
    const int rbase = bm + wm + i * 16 + quad * 4;
#pragma unroll
    for (int j = 0; j < 4; ++j) {
      const int col = bn + wn + j * 16 + m16;
      const float bvv = bias[col];
      if (EPI == 0) {
#pragma unroll
        for (int r = 0; r < 4; ++r)
          Cf[(size_t)(rbase + r) * N + col] = acc[i][j][r] + bvv;
      } else {
        const int type = col >> 11;       // block-uniform
        const int vcol = col & 2047;
        const int h = vcol >> 7, d = vcol & 127;
        const int b = rbase >> 11;
        if (type == 2) {
          // V -> Vt3 [bh][kb][d][ks'], ks-chunk swizzled by d&7
          const int s0 = rbase & 2047;
          const int kb = s0 >> 6, kse = s0 & 63;
          const int c8 = ((kse >> 3) ^ (d & 7));
          ushort4 pk;
          pk.x = f32_to_bf16(acc[i][j][0] + bvv);
          pk.y = f32_to_bf16(acc[i][j][1] + bvv);
          pk.z = f32_to_bf16(acc[i][j][2] + bvv);
          pk.w = f32_to_bf16(acc[i][j][3] + bvv);
          *reinterpret_cast<ushort4*>(
              Vo + (((size_t)(b * 16 + h) * 32 + kb) * 128 + d) * 64 +
              c8 * 8 + (kse & 7)) = pk;
        } else {
          const float scl2 = (type == 0) ? scl : 1.0f;
          const int pi = d >> 1;
#pragma unroll
          for (int r = 0; r < 4; ++r) {
            const int row = rbase + r;
            const int s = row & 2047;
            const float v = acc[i][j][r] + bvv;
            const float vp = __shfl_xor(v, 1);
            const float2 cs = tab[s * 64 + pi];
            const float oe = (v * cs.x - vp * cs.y) * scl2;
            const float oo = (vp * cs.x + v * cs.y) * scl2;
            if ((m16 & 1) == 0) {
              const unsigned pk2 = (unsigned)f32_to_bf16(oe) |
                                   ((unsigned)f32_to_bf16(oo) << 16);
              if (type == 0) {
                *reinterpret_cast<unsigned*>(Qo + (size_t)row * 2048 + vcol) =
                    pk2;
              } else {
                // Kh [bh][kt=s][d'], d-chunk swizzled by s&15
                const int dp = ((d >> 3) ^ (s & 15)) * 8 + (d & 7);
                *reinterpret_cast<unsigned*>(
                    Ko + ((size_t)(b * 16 + h) * 2048 + s) * 128 + dp) = pk2;
              }
            }
          }
        }
      }
    }
  }
}

// ---------------------------------------------------------------------------
// MFMA flash attention v2. 48KB LDS (3 blocks/CU), global_load_lds staging
// from tiled/swizzled Kh & Vt3, unpadded swizzled LDS, packed b32 P/O writes,
// heavy-diagonal blocks dispatched first. No-max log2-domain softmax.
// ---------------------------------------------------------------------------
constexpr int F_BQ = 128, F_BK = 64, F_DH = 128;

__global__ __launch_bounds__(256, 3) void fattn_kernel(
    const unsigned short* __restrict__ Qb, const unsigned short* __restrict__ Kh,
    const unsigned short* __restrict__ Vt3, unsigned short* __restrict__ Ob,
    int S, int H, int nh) {
  __shared__ unsigned short Ks[64 * 128];   // [kt][d']  16KB
  __shared__ unsigned short Vts[128 * 64];  // [d][ks']  16KB
  __shared__ unsigned short Ps[128 * 64];   // [q][kt']  16KB

  const int t = threadIdx.x;
  const int lane = t & 63;
  const int w = t >> 6;
  const int l15 = lane & 15;
  const int quad = lane >> 4;

  // heavy-first: i<256 -> qt 15..8, i>=256 -> qt 0..7
  const int i = blockIdx.x;
  const int bh = i & 31;
  const int qt = (i < 256) ? (15 - (i >> 5)) : ((i - 256) >> 5);
  const int h = bh & 15;
  const int b = bh >> 4;
  const int q0 = qt * F_BQ;

  const unsigned short* Qrow = Qb + ((size_t)(b * S + q0)) * H + h * F_DH;
  const unsigned short* Kbase = Kh + (size_t)bh * S * F_DH;
  const unsigned short* Vbase = Vt3 + (size_t)bh * 32 * 8192;
  unsigned short* Orow = Ob + ((size_t)(b * S + q0)) * H + h * F_DH;

  // persistent Q a-frags
  bf16x8 aq[2][4];
#pragma unroll
  for (int qg = 0; qg < 2; ++qg)
#pragma unroll
    for (int ks = 0; ks < 4; ++ks)
      aq[qg][ks] = *reinterpret_cast<const bf16x8*>(
          Qrow + (size_t)(w * 32 + qg * 16 + l15) * H + ks * 32 + quad * 8);

  floatx4 oacc[2][8];
#pragma unroll
  for (int qg = 0; qg < 2; ++qg)
#pragma unroll
    for (int dj = 0; dj < 8; ++dj) oacc[qg][dj] = floatx4{0.f, 0.f, 0.f, 0.f};
  float lpart[2][4] = {{0.f, 0.f, 0.f, 0.f}, {0.f, 0.f, 0.f, 0.f}};
  int qrow[2][4];
#pragma unroll
  for (int qg = 0; qg < 2; ++qg)
#pragma unroll
    for (int r = 0; r < 4; ++r)
      qrow[qg][r] = q0 + w * 32 + qg * 16 + quad * 4 + r;

  const int lofs = lane * 8;  // per-lane 16B offset for gld_lds16 (THE FIX)

  const int ntile = q0 / F_BK + 2;
  for (int tile = 0; tile < ntile; ++tile) {
    const int k0 = tile * F_BK;
    __syncthreads();  // prev-tile readers of Ks/Vts done
    {
      const unsigned short* Ktile = Kbase + (size_t)k0 * 128;
      const unsigned short* Vtile = Vbase + (size_t)(k0 >> 6) * 8192;
#pragma unroll
      for (int it = 0; it < 4; ++it) {
        gld_lds16(Ktile + w * 2048 + it * 512 + lofs,
                  &Ks[w * 2048 + it * 512]);
        gld_lds16(Vtile + w * 2048 + it * 512 + lofs,
                  &Vts[w * 2048 + it * 512]);
      }
    }
    __syncthreads();  // vmcnt(0) drain

    // S = Q.K^T : D[m=q][n=kt], k=d (chunks d-swizzled by row&15 = l15)
    floatx4 sacc[2][4];
#pragma unroll
    for (int qg = 0; qg < 2; ++qg)
#pragma unroll
      for (int j = 0; j < 4; ++j) sacc[qg][j] = floatx4{0.f, 0.f, 0.f, 0.f};
#pragma unroll
    for (int j = 0; j < 4; ++j) {
      bf16x8 bk[4];
#pragma unroll
      for (int ks = 0; ks < 4; ++ks)
        bk[ks] = *reinterpret_cast<const bf16x8*>(
            &Ks[(j * 16 + l15) * 128 + (((ks * 4 + quad) ^ l15) * 8)]);
#pragma unroll
      for (int qg = 0; qg < 2; ++qg)
#pragma unroll
        for (int ks = 0; ks < 4; ++ks)
          sacc[qg][j] = __builtin_amdgcn_mfma_f32_16x16x32_bf16(
              aq[qg][ks], bk[ks], sacc[qg][j], 0, 0, 0);
    }

    // mask + exp2 + lane-local l; packed b32 P writes (kt-chunk swizzled)
#pragma unroll
    for (int qg = 0; qg < 2; ++qg)
#pragma unroll
      for (int j = 0; j < 4; ++j) {
        const int ktg = k0 + j * 16 + l15;
        const int cw = j * 2 + (l15 >> 3);
#pragma unroll
        for (int r = 0; r < 4; ++r) {
          const float p =
              (ktg <= qrow[qg][r]) ? exp2f(sacc[qg][j][r]) : 0.0f;
          lpart[qg][r] += p;
          const float pp = __shfl_xor(p, 1);
          if ((l15 & 1) == 0) {
            const int prow = w * 32 + qg * 16 + quad * 4 + r;
            const int cwp = cw ^ (prow & 7);
            const unsigned pk = (unsigned)f32_to_bf16(p) |
                                ((unsigned)f32_to_bf16(pp) << 16);
            *reinterpret_cast<unsigned*>(
                &Ps[prow * 64 + cwp * 8 + (l15 & 7)]) = pk;
          }
        }
      }

    // O += P.V : D[m=q][n=d], k=kt  (Ps wave-private: no barrier)
#pragma unroll
    for (int ks2 = 0; ks2 < 2; ++ks2) {
      bf16x8 ap[2];
#pragma unroll
      for (int qg = 0; qg < 2; ++qg)
        ap[qg] = *reinterpret_cast<const bf16x8*>(
            &Ps[(w * 32 + qg * 16 + l15) * 64 +
                (((ks2 * 4 + quad) ^ (l15 & 7)) * 8)]);
#pragma unroll
      for (int dj = 0; dj < 8; ++dj) {
        const bf16x8 bv = *reinterpret_cast<const bf16x8*>(
            &Vts[(dj * 16 + l15) * 64 +
                 (((ks2 * 4 + quad) ^ (l15 & 7)) * 8)]);
#pragma unroll
        for (int qg = 0; qg < 2; ++qg)
          oacc[qg][dj] = __builtin_amdgcn_mfma_f32_16x16x32_bf16(
              ap[qg], bv, oacc[qg][dj], 0, 0, 0);
      }
    }
  }

  // final l reduction + packed O write (bf16)
#pragma unroll
  for (int qg = 0; qg < 2; ++qg)
#pragma unroll
    for (int r = 0; r < 4; ++r) {
      float l = lpart[qg][r];
      l += __shfl_xor(l, 1);
      l += __shfl_xor(l, 2);
      l += __shfl_xor(l, 4);
      l += __shfl_xor(l, 8);
      const float linv = 1.0f / l;
      unsigned short* orow =
          Orow + (size_t)(w * 32 + qg * 16 + quad * 4 + r) * H;
#pragma unroll
      for (int dj = 0; dj < 8; ++dj) {
        const float o = oacc[qg][dj][r] * linv;
        const float op = __shfl_xor(o, 1);
        if ((l15 & 1) == 0) {
          const unsigned pk = (unsigned)f32_to_bf16(o) |
                              ((unsigned)f32_to_bf16(op) << 16);
          *reinterpret_cast<unsigned*>(orow + dj * 16 + l15) = pk;
        }
      }
    }
}

// ---------------------------------------------------------------------------
// Launch
// ---------------------------------------------------------------------------
extern "C" void kernel_launch(void* const* d_in, const int* in_sizes, int n_in,
                              void* d_out, int out_size, void* d_ws,
                              size_t ws_size, hipStream_t stream) {
  const float* x  = (const float*)d_in[0];
  const float* Wq = (const float*)d_in[1];
  const float* bq = (const float*)d_in[2];
  const float* Wk = (const float*)d_in[3];
  const float* bk = (const float*)d_in[4];
  const float* Wv = (const float*)d_in[5];
  const float* bv = (const float*)d_in[6];
  const float* Wo = (const float*)d_in[7];
  const float* bo = (const float*)d_in[8];
  float* out = (float*)d_out;

  const int B = 2, S = 2048, H = 2048, nh = 16;
  const int M = B * S;  // 4096

  // workspace (~103 MB)
  unsigned short* Wqkvb = (unsigned short*)d_ws;            // 3*H*H
  unsigned short* Wob = Wqkvb + (size_t)3 * H * H;
  unsigned short* xb  = Wob + (size_t)H * H;
  unsigned short* Qbb = xb + (size_t)M * H;
  unsigned short* Kh  = Qbb + (size_t)M * H;
  unsigned short* Vt3 = Kh + (size_t)M * H;
  unsigned short* Ob  = Vt3 + (size_t)M * H;
  float* bqkv = (float*)(Ob + (size_t)M * H);               // 6144 floats
  float2* tab = (float2*)(bqkv + 6144);                     // S*64 float2 = 1 MB

  const int cast_w4 = H * H / 4;   // 1,048,576
  const int cast_x4 = M * H / 4;   // 2,097,152
  const int tab_n = S * 64;

  rope_table_kernel<<<dim3(tab_n / 256), dim3(256), 0, stream>>>(tab, tab_n);
  bcat_kernel<<<dim3(6144 / 256), dim3(256), 0, stream>>>(bq, bk, bv, bqkv);
  cast3_kernel<<<dim3(3 * cast_w4 / 256), dim3(256), 0, stream>>>(
      Wq, Wk, Wv, Wqkvb, cast_w4);
  cast_kernel<<<dim3(cast_w4 / 256), dim3(256), 0, stream>>>(Wo, Wob, cast_w4);
  cast_kernel<<<dim3(cast_x4 / 256), dim3(256), 0, stream>>>(x, xb, cast_x4);

  const float qscale = 0.08838834764831845f * 1.4426950408889634f;

  // QKV mega-GEMM: N = 6144, 1536 blocks
  gemm_fused<1><<<dim3(3 * H / 128, M / 128), dim3(256), 0, stream>>>(
      xb, Wqkvb, bqkv, nullptr, Qbb, Kh, Vt3, tab, qscale, M, 3 * H, H);

  fattn_kernel<<<dim3((S / F_BQ) * B * nh), dim3(256), 0, stream>>>(
      Qbb, Kh, Vt3, Ob, S, H, nh);

  gemm_fused<0><<<dim3(H / 128, M / 128), dim3(256), 0, stream>>>(
      Ob, Wob, bo, out, nullptr, nullptr, nullptr, nullptr, 1.0f, M, H, H);
}

// Round 7
// 494.268 us; speedup vs baseline: 1.2792x; 1.2792x over previous
//
#include <hip/hip_runtime.h>
#include <math.h>

// ---------------------------------------------------------------------------
// Types / helpers
// ---------------------------------------------------------------------------
typedef __bf16 bf16x8 __attribute__((ext_vector_type(8)));
typedef float floatx4 __attribute__((ext_vector_type(4)));

__device__ __forceinline__ unsigned short f32_to_bf16(float f) {
  unsigned int u = __float_as_uint(f);
  u = u + 0x7FFFu + ((u >> 16) & 1u);   // RNE; inputs finite
  return (unsigned short)(u >> 16);
}

// async global->LDS, 16B/lane. GLOBAL ptr must include the per-lane offset
// (lane*8 shorts); LDS base is wave-uniform, HW scatters lane i to +i*16B.
__device__ __forceinline__ void gld_lds16(const unsigned short* g,
                                          unsigned short* l) {
  __builtin_amdgcn_global_load_lds(
      (const __attribute__((address_space(1))) unsigned int*)g,
      (__attribute__((address_space(3))) unsigned int*)l, 16, 0, 0);
}

// ---------------------------------------------------------------------------
// fp32 -> bf16 cast (float4 -> ushort4)
// ---------------------------------------------------------------------------
__global__ void cast_kernel(const float* __restrict__ in,
                            unsigned short* __restrict__ out, int n4) {
  int i = blockIdx.x * blockDim.x + threadIdx.x;
  if (i >= n4) return;
  const float4 v = reinterpret_cast<const float4*>(in)[i];
  ushort4 o;
  o.x = f32_to_bf16(v.x); o.y = f32_to_bf16(v.y);
  o.z = f32_to_bf16(v.z); o.w = f32_to_bf16(v.w);
  reinterpret_cast<ushort4*>(out)[i] = o;
}

// three weights -> one concatenated bf16 buffer [Wq;Wk;Wv] (6144 x 2048)
__global__ void cast3_kernel(const float* __restrict__ w0,
                             const float* __restrict__ w1,
                             const float* __restrict__ w2,
                             unsigned short* __restrict__ out, int n4each) {
  int i = blockIdx.x * blockDim.x + threadIdx.x;
  if (i >= 3 * n4each) return;
  const int which = i / n4each;
  const int off = i - which * n4each;
  const float* src = (which == 0) ? w0 : (which == 1) ? w1 : w2;
  const float4 v = reinterpret_cast<const float4*>(src)[off];
  ushort4 o;
  o.x = f32_to_bf16(v.x); o.y = f32_to_bf16(v.y);
  o.z = f32_to_bf16(v.z); o.w = f32_to_bf16(v.w);
  reinterpret_cast<ushort4*>(out)[i] = o;
}

// bias concat: bqkv[0:2048)=bq, [2048:4096)=bk, [4096:6144)=bv
__global__ void bcat_kernel(const float* __restrict__ bq,
                            const float* __restrict__ bk,
                            const float* __restrict__ bv,
                            float* __restrict__ out) {
  int i = blockIdx.x * blockDim.x + threadIdx.x;  // 0..6143
  const int which = i >> 11, off = i & 2047;
  out[i] = (which == 0) ? bq[off] : (which == 1) ? bk[off] : bv[off];
}

// ---------------------------------------------------------------------------
// RoPE cos/sin table: tab[s*64+i] = (cos, sin) of s / 10000^(i/64).
// Built with libm cosf/sinf (full range reduction) — native v_sin/v_cos are
// only valid to ~±1608 rad and angles here reach 2047 rad.
// ---------------------------------------------------------------------------
__global__ void rope_table_kernel(float2* __restrict__ tab, int total) {
  int idx = blockIdx.x * blockDim.x + threadIdx.x;
  if (idx >= total) return;
  const int s = idx >> 6, i = idx & 63;
  const float inv = powf(10000.0f, -(float)i * (1.0f / 64.0f));
  const float ang = (float)s * inv;
  tab[idx] = make_float2(cosf(ang), sinf(ang));
}

// ---------------------------------------------------------------------------
// Fused GEMM: C[m][n] = sum_k A[m][k]*B[n][k] + bias[n]
// 128x128 tile, BK=64, 4 waves, 4x4 of 16x16x32 MFMA. global_load_lds
// staging into unpadded LDS with XOR chunk swizzle on the GLOBAL address.
// EPI=0: fp32 out + bias (N=2048).
// EPI=1: QKV mega-GEMM (N=6144). Per col>>11:
//   0 -> RoPE (table) * qscale -> Qbb row-major [m][2048]
//   1 -> RoPE (table) -> Kh [bh][kt][d'] with d-chunk swizzle (key kt&15)
//   2 -> Vt3 [bh][kb][d][ks'] with ks-chunk swizzle (key d&7)
// ---------------------------------------------------------------------------
template <int EPI>
__global__ __launch_bounds__(256) void gemm_fused(
    const unsigned short* __restrict__ A, const unsigned short* __restrict__ B,
    const float* __restrict__ bias, float* __restrict__ Cf,
    unsigned short* __restrict__ Qo, unsigned short* __restrict__ Ko,
    unsigned short* __restrict__ Vo, const float2* __restrict__ tab,
    float scl, int M, int N, int K) {
  __shared__ unsigned short As[128 * 64];
  __shared__ unsigned short Bs[128 * 64];
  const int t = threadIdx.x;
  const int lane = t & 63;
  const int w = t >> 6;
  const int bm = blockIdx.y * 128;
  const int bn = blockIdx.x * 128;
  const int wm = (w & 1) * 64;
  const int wn = (w >> 1) * 64;
  const int m16 = lane & 15;
  const int quad = lane >> 4;
  const int key = m16 & 7;

  const int lr = lane >> 3;
  const int lc = ((lane & 7) ^ lr) * 8;

  floatx4 acc[4][4];
#pragma unroll
  for (int i = 0; i < 4; ++i)
#pragma unroll
    for (int j = 0; j < 4; ++j) acc[i][j] = floatx4{0.f, 0.f, 0.f, 0.f};

  const unsigned short* Abase = A + (size_t)(bm + w * 32 + lr) * K + lc;
  const unsigned short* Bbase = B + (size_t)(bn + w * 32 + lr) * K + lc;

  for (int k0 = 0; k0 < K; k0 += 64) {
    __syncthreads();
#pragma unroll
    for (int it = 0; it < 4; ++it) {
      gld_lds16(Abase + (size_t)it * 8 * K + k0, &As[(w * 4 + it) * 512]);
      gld_lds16(Bbase + (size_t)it * 8 * K + k0, &Bs[(w * 4 + it) * 512]);
    }
    __syncthreads();
#pragma unroll
    for (int ks = 0; ks < 64; ks += 32) {
      const int ck = ks >> 3;  // 0 or 4
      bf16x8 af[4], bfr[4];
#pragma unroll
      for (int i = 0; i < 4; ++i)
        af[i] = *reinterpret_cast<const bf16x8*>(
            &As[(wm + i * 16 + m16) * 64 + ((ck | quad) ^ key) * 8]);
#pragma unroll
      for (int j = 0; j < 4; ++j)
        bfr[j] = *reinterpret_cast<const bf16x8*>(
            &Bs[(wn + j * 16 + m16) * 64 + ((ck | quad) ^ key) * 8]);
#pragma unroll
      for (int i = 0; i < 4; ++i)
#pragma unroll
        for (int j = 0; j < 4; ++j)
          acc[i][j] = __builtin_amdgcn_mfma_f32_16x16x32_bf16(
              af[i], bfr[j], acc[i][j], 0, 0, 0);
    }
  }

  // epilogue: C/D layout col=lane&15, row=quad*4+reg  [m89/m91 verified]
#pragma unroll
  for (int i = 0; i < 4; ++i) {
    const int rbase = bm + wm + i * 16 + quad * 4;
#pragma unroll
    for (int j = 0; j < 4; ++j) {
      const int col = bn + wn + j * 16 + m16;
      const float bvv = bias[col];
      if (EPI == 0) {
#pragma unroll
        for (int r = 0; r < 4; ++r)
          Cf[(size_t)(rbase + r) * N + col] = acc[i][j][r] + bvv;
      } else {
        const int type = col >> 11;       // block-uniform
        const int vcol = col & 2047;
        const int h = vcol >> 7, d = vcol & 127;
        const int b = rbase >> 11;
        if (type == 2) {
          // V -> Vt3 [bh][kb][d][ks'], ks-chunk swizzled by d&7
          const int s0 = rbase & 2047;
          const int kb = s0 >> 6, kse = s0 & 63;
          const int c8 = ((kse >> 3) ^ (d & 7));
          ushort4 pk;
          pk.x = f32_to_bf16(acc[i][j][0] + bvv);
          pk.y = f32_to_bf16(acc[i][j][1] + bvv);
          pk.z = f32_to_bf16(acc[i][j][2] + bvv);
          pk.w = f32_to_bf16(acc[i][j][3] + bvv);
          *reinterpret_cast<ushort4*>(
              Vo + (((size_t)(b * 16 + h) * 32 + kb) * 128 + d) * 64 +
              c8 * 8 + (kse & 7)) = pk;
        } else {
          const float scl2 = (type == 0) ? scl : 1.0f;
          const int pi = d >> 1;
#pragma unroll
          for (int r = 0; r < 4; ++r) {
            const int row = rbase + r;
            const int s = row & 2047;
            const float v = acc[i][j][r] + bvv;
            const float vp = __shfl_xor(v, 1);
            const float2 cs = tab[s * 64 + pi];
            const float oe = (v * cs.x - vp * cs.y) * scl2;
            const float oo = (vp * cs.x + v * cs.y) * scl2;
            if ((m16 & 1) == 0) {
              const unsigned pk2 = (unsigned)f32_to_bf16(oe) |
                                   ((unsigned)f32_to_bf16(oo) << 16);
              if (type == 0) {
                *reinterpret_cast<unsigned*>(Qo + (size_t)row * 2048 + vcol) =
                    pk2;
              } else {
                // Kh [bh][kt=s][d'], d-chunk swizzled by s&15
                const int dp = ((d >> 3) ^ (s & 15)) * 8 + (d & 7);
                *reinterpret_cast<unsigned*>(
                    Ko + ((size_t)(b * 16 + h) * 2048 + s) * 128 + dp) = pk2;
              }
            }
          }
        }
      }
    }
  }
}

// ---------------------------------------------------------------------------
// MFMA flash attention v2. 48KB LDS, global_load_lds staging from tiled
// swizzled Kh & Vt3, unpadded swizzled LDS, packed b32 P/O writes,
// heavy-diagonal blocks dispatched first. No-max log2-domain softmax.
// __launch_bounds__(256,2): grid=512 is exactly 2 blocks/CU, so capacity-3
// buys nothing; R6's (256,3) starved registers (VGPR 84 < 96 live regs ->
// accumulator spills -> 25MB scratch writes, fattn 97->277us regression).
// ---------------------------------------------------------------------------
constexpr int F_BQ = 128, F_BK = 64, F_DH = 128;

__global__ __launch_bounds__(256, 2) void fattn_kernel(
    const unsigned short* __restrict__ Qb, const unsigned short* __restrict__ Kh,
    const unsigned short* __restrict__ Vt3, unsigned short* __restrict__ Ob,
    int S, int H, int nh) {
  __shared__ unsigned short Ks[64 * 128];   // [kt][d']  16KB
  __shared__ unsigned short Vts[128 * 64];  // [d][ks']  16KB
  __shared__ unsigned short Ps[128 * 64];   // [q][kt']  16KB

  const int t = threadIdx.x;
  const int lane = t & 63;
  const int w = t >> 6;
  const int l15 = lane & 15;
  const int quad = lane >> 4;

  // heavy-first: i<256 -> qt 15..8, i>=256 -> qt 0..7
  const int i = blockIdx.x;
  const int bh = i & 31;
  const int qt = (i < 256) ? (15 - (i >> 5)) : ((i - 256) >> 5);
  const int h = bh & 15;
  const int b = bh >> 4;
  const int q0 = qt * F_BQ;

  const unsigned short* Qrow = Qb + ((size_t)(b * S + q0)) * H + h * F_DH;
  const unsigned short* Kbase = Kh + (size_t)bh * S * F_DH;
  const unsigned short* Vbase = Vt3 + (size_t)bh * 32 * 8192;
  unsigned short* Orow = Ob + ((size_t)(b * S + q0)) * H + h * F_DH;

  // persistent Q a-frags
  bf16x8 aq[2][4];
#pragma unroll
  for (int qg = 0; qg < 2; ++qg)
#pragma unroll
    for (int ks = 0; ks < 4; ++ks)
      aq[qg][ks] = *reinterpret_cast<const bf16x8*>(
          Qrow + (size_t)(w * 32 + qg * 16 + l15) * H + ks * 32 + quad * 8);

  floatx4 oacc[2][8];
#pragma unroll
  for (int qg = 0; qg < 2; ++qg)
#pragma unroll
    for (int dj = 0; dj < 8; ++dj) oacc[qg][dj] = floatx4{0.f, 0.f, 0.f, 0.f};
  float lpart[2][4] = {{0.f, 0.f, 0.f, 0.f}, {0.f, 0.f, 0.f, 0.f}};
  int qrow[2][4];
#pragma unroll
  for (int qg = 0; qg < 2; ++qg)
#pragma unroll
    for (int r = 0; r < 4; ++r)
      qrow[qg][r] = q0 + w * 32 + qg * 16 + quad * 4 + r;

  const int lofs = lane * 8;  // per-lane 16B offset for gld_lds16

  const int ntile = q0 / F_BK + 2;
  for (int tile = 0; tile < ntile; ++tile) {
    const int k0 = tile * F_BK;
    __syncthreads();  // prev-tile readers of Ks/Vts done
    {
      const unsigned short* Ktile = Kbase + (size_t)k0 * 128;
      const unsigned short* Vtile = Vbase + (size_t)(k0 >> 6) * 8192;
#pragma unroll
      for (int it = 0; it < 4; ++it) {
        gld_lds16(Ktile + w * 2048 + it * 512 + lofs,
                  &Ks[w * 2048 + it * 512]);
        gld_lds16(Vtile + w * 2048 + it * 512 + lofs,
                  &Vts[w * 2048 + it * 512]);
      }
    }
    __syncthreads();  // vmcnt(0) drain

    // S = Q.K^T : D[m=q][n=kt], k=d (chunks d-swizzled by row&15 = l15)
    floatx4 sacc[2][4];
#pragma unroll
    for (int qg = 0; qg < 2; ++qg)
#pragma unroll
      for (int j = 0; j < 4; ++j) sacc[qg][j] = floatx4{0.f, 0.f, 0.f, 0.f};
#pragma unroll
    for (int j = 0; j < 4; ++j) {
      bf16x8 bk[4];
#pragma unroll
      for (int ks = 0; ks < 4; ++ks)
        bk[ks] = *reinterpret_cast<const bf16x8*>(
            &Ks[(j * 16 + l15) * 128 + (((ks * 4 + quad) ^ l15) * 8)]);
#pragma unroll
      for (int qg = 0; qg < 2; ++qg)
#pragma unroll
        for (int ks = 0; ks < 4; ++ks)
          sacc[qg][j] = __builtin_amdgcn_mfma_f32_16x16x32_bf16(
              aq[qg][ks], bk[ks], sacc[qg][j], 0, 0, 0);
    }

    // mask + exp2 + lane-local l; packed b32 P writes (kt-chunk swizzled)
#pragma unroll
    for (int qg = 0; qg < 2; ++qg)
#pragma unroll
      for (int j = 0; j < 4; ++j) {
        const int ktg = k0 + j * 16 + l15;
        const int cw = j * 2 + (l15 >> 3);
#pragma unroll
        for (int r = 0; r < 4; ++r) {
          const float p =
              (ktg <= qrow[qg][r]) ? exp2f(sacc[qg][j][r]) : 0.0f;
          lpart[qg][r] += p;
          const float pp = __shfl_xor(p, 1);
          if ((l15 & 1) == 0) {
            const int prow = w * 32 + qg * 16 + quad * 4 + r;
            const int cwp = cw ^ (prow & 7);
            const unsigned pk = (unsigned)f32_to_bf16(p) |
                                ((unsigned)f32_to_bf16(pp) << 16);
            *reinterpret_cast<unsigned*>(
                &Ps[prow * 64 + cwp * 8 + (l15 & 7)]) = pk;
          }
        }
      }

    // O += P.V : D[m=q][n=d], k=kt  (Ps wave-private: no barrier)
#pragma unroll
    for (int ks2 = 0; ks2 < 2; ++ks2) {
      bf16x8 ap[2];
#pragma unroll
      for (int qg = 0; qg < 2; ++qg)
        ap[qg] = *reinterpret_cast<const bf16x8*>(
            &Ps[(w * 32 + qg * 16 + l15) * 64 +
                (((ks2 * 4 + quad) ^ (l15 & 7)) * 8)]);
#pragma unroll
      for (int dj = 0; dj < 8; ++dj) {
        const bf16x8 bv = *reinterpret_cast<const bf16x8*>(
            &Vts[(dj * 16 + l15) * 64 +
                 (((ks2 * 4 + quad) ^ (l15 & 7)) * 8)]);
#pragma unroll
        for (int qg = 0; qg < 2; ++qg)
          oacc[qg][dj] = __builtin_amdgcn_mfma_f32_16x16x32_bf16(
              ap[qg], bv, oacc[qg][dj], 0, 0, 0);
      }
    }
  }

  // final l reduction + packed O write (bf16)
#pragma unroll
  for (int qg = 0; qg < 2; ++qg)
#pragma unroll
    for (int r = 0; r < 4; ++r) {
      float l = lpart[qg][r];
      l += __shfl_xor(l, 1);
      l += __shfl_xor(l, 2);
      l += __shfl_xor(l, 4);
      l += __shfl_xor(l, 8);
      const float linv = 1.0f / l;
      unsigned short* orow =
          Orow + (size_t)(w * 32 + qg * 16 + quad * 4 + r) * H;
#pragma unroll
      for (int dj = 0; dj < 8; ++dj) {
        const float o = oacc[qg][dj][r] * linv;
        const float op = __shfl_xor(o, 1);
        if ((l15 & 1) == 0) {
          const unsigned pk = (unsigned)f32_to_bf16(o) |
                              ((unsigned)f32_to_bf16(op) << 16);
          *reinterpret_cast<unsigned*>(orow + dj * 16 + l15) = pk;
        }
      }
    }
}

// ---------------------------------------------------------------------------
// Launch
// ---------------------------------------------------------------------------
extern "C" void kernel_launch(void* const* d_in, const int* in_sizes, int n_in,
                              void* d_out, int out_size, void* d_ws,
                              size_t ws_size, hipStream_t stream) {
  const float* x  = (const float*)d_in[0];
  const float* Wq = (const float*)d_in[1];
  const float* bq = (const float*)d_in[2];
  const float* Wk = (const float*)d_in[3];
  const float* bk = (const float*)d_in[4];
  const float* Wv = (const float*)d_in[5];
  const float* bv = (const float*)d_in[6];
  const float* Wo = (const float*)d_in[7];
  const float* bo = (const float*)d_in[8];
  float* out = (float*)d_out;

  const int B = 2, S = 2048, H = 2048, nh = 16;
  const int M = B * S;  // 4096

  // workspace (~103 MB)
  unsigned short* Wqkvb = (unsigned short*)d_ws;            // 3*H*H
  unsigned short* Wob = Wqkvb + (size_t)3 * H * H;
  unsigned short* xb  = Wob + (size_t)H * H;
  unsigned short* Qbb = xb + (size_t)M * H;
  unsigned short* Kh  = Qbb + (size_t)M * H;
  unsigned short* Vt3 = Kh + (size_t)M * H;
  unsigned short* Ob  = Vt3 + (size_t)M * H;
  float* bqkv = (float*)(Ob + (size_t)M * H);               // 6144 floats
  float2* tab = (float2*)(bqkv + 6144);                     // S*64 float2 = 1 MB

  const int cast_w4 = H * H / 4;   // 1,048,576
  const int cast_x4 = M * H / 4;   // 2,097,152
  const int tab_n = S * 64;

  rope_table_kernel<<<dim3(tab_n / 256), dim3(256), 0, stream>>>(tab, tab_n);
  bcat_kernel<<<dim3(6144 / 256), dim3(256), 0, stream>>>(bq, bk, bv, bqkv);
  cast3_kernel<<<dim3(3 * cast_w4 / 256), dim3(256), 0, stream>>>(
      Wq, Wk, Wv, Wqkvb, cast_w4);
  cast_kernel<<<dim3(cast_w4 / 256), dim3(256), 0, stream>>>(Wo, Wob, cast_w4);
  cast_kernel<<<dim3(cast_x4 / 256), dim3(256), 0, stream>>>(x, xb, cast_x4);

  const float qscale = 0.08838834764831845f * 1.4426950408889634f;

  // QKV mega-GEMM: N = 6144, 1536 blocks
  gemm_fused<1><<<dim3(3 * H / 128, M / 128), dim3(256), 0, stream>>>(
      xb, Wqkvb, bqkv, nullptr, Qbb, Kh, Vt3, tab, qscale, M, 3 * H, H);

  fattn_kernel<<<dim3((S / F_BQ) * B * nh), dim3(256), 0, stream>>>(
      Qbb, Kh, Vt3, Ob, S, H, nh);

  gemm_fused<0><<<dim3(H / 128, M / 128), dim3(256), 0, stream>>>(
      Ob, Wob, bo, out, nullptr, nullptr, nullptr, nullptr, 1.0f, M, H, H);
}